// Round 6
// baseline (62.087 us; speedup 1.0000x reference)
//
#include <hip/hip_runtime.h>
#include <hip/hip_bf16.h>
#include <stdint.h>

#define B_ 8
#define N_ 2048
#define F_ 128
#define D_ 128

typedef short bf16x8 __attribute__((ext_vector_type(8)));
typedef float f32x4 __attribute__((ext_vector_type(4)));

__device__ __forceinline__ unsigned short f2bf(float f) {
    unsigned u = __float_as_uint(f);
    u += 0x7fffu + ((u >> 16) & 1u);
    return (unsigned short)(u >> 16);
}

// ---------------- Kernel 1: feat (blocks 0..255) + degrees (blocks 256..4351) ----------------
// feat: gt[b][d][m] = (X@W + bias)^T bf16, UNscaled (no rs dependency -> runs concurrent w/ deg).
// deg: one wave per adj row -> rs.
__global__ __launch_bounds__(256) void k_degfeat(const float* __restrict__ adj,
                                                 const float* __restrict__ x,
                                                 const float* __restrict__ W,
                                                 const float* __restrict__ bias,
                                                 float* __restrict__ rs,
                                                 unsigned short* __restrict__ gt) {
    __shared__ __align__(16) unsigned char sX[64 * 128 * 2];   // feat only
    __shared__ __align__(16) unsigned char sW[128 * 128 * 2];  // feat only: W^T [d][f] bf16 swz

    const int t = threadIdx.x;
    if (blockIdx.x >= 256) {
        // ---- degree path ----
        const int wave = t >> 6, lane = t & 63;
        const int row = (blockIdx.x - 256) * 4 + wave;   // 0..B_*N_-1
        const float4* p = (const float4*)(adj + (size_t)row * N_);
        float s = 0.f;
#pragma unroll
        for (int j = 0; j < 8; ++j) {
            float4 v = p[j * 64 + lane];
            s += (v.x + v.y) + (v.z + v.w);
        }
#pragma unroll
        for (int m = 1; m < 64; m <<= 1) s += __shfl_xor(s, m, 64);
        if (lane == 0) rs[row] = (s > 0.f) ? (1.0f / sqrtf(s)) : 0.f;
        return;
    }

    // ---- feat path ----
    const int R0 = blockIdx.x * 64;

    // build sW = W^T [d][f] bf16 swizzled: coalesced W read, scattered b16 LDS writes
#pragma unroll
    for (int i = 0; i < 16; ++i) {
        int c = i * 256 + t;              // 4096 chunks
        int f = c >> 5, d0 = (c & 31) * 4;
        float4 v = *(const float4*)(W + (size_t)f * D_ + d0);
        float vv[4] = {v.x, v.y, v.z, v.w};
#pragma unroll
        for (int e = 0; e < 4; ++e) {
            int dd = d0 + e;
            unsigned byte = (unsigned)(dd * 256 + f * 2);
            byte ^= ((byte >> 8) & 15u) << 4;
            *(unsigned short*)(sW + byte) = f2bf(vv[e]);
        }
    }
    // stage X rows R0..R0+63 -> sX bf16 swz
#pragma unroll
    for (int j = 0; j < 4; ++j) {
        int c = j * 256 + t;
        int row = c >> 4, sub = c & 15;
        const float4* src = (const float4*)(x + (size_t)(R0 + row) * F_ + sub * 8);
        float4 v0 = src[0], v1 = src[1];
        union { bf16x8 v; unsigned short u[8]; } pk;
        pk.u[0] = f2bf(v0.x); pk.u[1] = f2bf(v0.y); pk.u[2] = f2bf(v0.z); pk.u[3] = f2bf(v0.w);
        pk.u[4] = f2bf(v1.x); pk.u[5] = f2bf(v1.y); pk.u[6] = f2bf(v1.z); pk.u[7] = f2bf(v1.w);
        unsigned byte = (unsigned)(row * 256 + sub * 16);
        byte ^= ((byte >> 8) & 7u) << 4;
        *(bf16x8*)(sX + byte) = pk.v;
    }
    __syncthreads();

    const int w = t >> 6, l = t & 63, lr = l & 15, lh = l >> 4;
    f32x4 acc[8];
#pragma unroll
    for (int j = 0; j < 8; ++j) acc[j] = (f32x4){0.f, 0.f, 0.f, 0.f};

#pragma unroll
    for (int ks = 0; ks < 4; ++ks) {
        unsigned abyte = (unsigned)((w * 16 + lr) * 256 + lh * 16 + ks * 64);
        abyte ^= ((abyte >> 8) & 7u) << 4;
        bf16x8 a = *(const bf16x8*)(sX + abyte);
#pragma unroll
        for (int j = 0; j < 8; ++j) {
            unsigned bbyte = (unsigned)((j * 16 + lr) * 256 + lh * 16 + ks * 64);
            bbyte ^= ((bbyte >> 8) & 15u) << 4;
            bf16x8 bb = *(const bf16x8*)(sW + bbyte);
            acc[j] = __builtin_amdgcn_mfma_f32_16x16x32_bf16(a, bb, acc[j], 0, 0, 0);
        }
    }

#pragma unroll
    for (int j = 0; j < 8; ++j) {
        int d = j * 16 + lr;
        float bv = bias[d];
#pragma unroll
        for (int r = 0; r < 4; ++r) {
            int m = R0 + w * 16 + lh * 4 + r;
            int b = m >> 11, n = m & (N_ - 1);
            gt[((size_t)b * D_ + d) * N_ + n] = f2bf(acc[j][r] + bv);
        }
    }
}

// ---------------- Kernel 2: out = relu(rs[n] * (adj*rs[m]) @ gt^T) ----------------
// 256 blocks (1/CU, 32/XCD, batch==XCD), 512 thr, BM=64 BN=128 BK=128.
// 8 waves = 2x4 grid of 32x32 tiles, full K per wave. Counted-vmcnt pipeline:
// per stage exactly 8 VMEM (4 gload_lds B + 4 dwordx4 A->reg), vmcnt(8) steady,
// rs[m] folded into A's fp32->bf16 convert (write-late, T14).
__global__ __launch_bounds__(512) void k_gcn(const float* __restrict__ adj,
                                             const unsigned short* __restrict__ gt,
                                             const float* __restrict__ rs,
                                             float* __restrict__ out) {
    __shared__ __align__(16) unsigned char sA[2][64 * 256];    // 2 x 16 KB bf16 (256B rows, swz)
    __shared__ __align__(16) unsigned char sB[2][128 * 256];   // 2 x 32 KB bf16 (256B rows, swz)
    __shared__ __align__(16) float sRS[N_];                    // 8 KB  (total 104 KB)

    unsigned bid = blockIdx.x;
    unsigned wg = (bid & 7u) * 32u + (bid >> 3);
    const int b = (int)(wg >> 5);
    const int R0 = (int)(wg & 31u) * 64;

    const float* adjB = adj + (size_t)b * N_ * N_ + (size_t)R0 * N_;
    const unsigned short* gtB = gt + (size_t)b * D_ * N_;
    const float* rsB = rs + (size_t)b * N_;

    const int t = threadIdx.x;
    const int w = t >> 6, l = t & 63, lr = l & 15, lh = l >> 4;
    const int wr = w >> 2, wc = w & 3;    // wave tile rows wr*32..+32, cols wc*32..+32

    // ---- B geometry: 4 chunks/thread, linear LDS dest + inverse-swizzled global src ----
    const unsigned short* bSrc[4];
    unsigned bL[4];
#pragma unroll
    for (int i = 0; i < 4; ++i) {
        unsigned c = (unsigned)(i * 512 + t);
        unsigned L = c * 16u;
        unsigned lg = L ^ (((L >> 8) & 7u) << 4);
        bL[i] = L;
        bSrc[i] = gtB + (size_t)(lg >> 8) * N_ + ((lg & 255u) >> 1);
    }
    auto issueB = [&](int buf, int k0) {
        unsigned char* pB = sB[buf];
#pragma unroll
        for (int i = 0; i < 4; ++i) {
            __builtin_amdgcn_global_load_lds(
                (const __attribute__((address_space(1))) void*)(bSrc[i] + k0),
                (__attribute__((address_space(3))) void*)(pB + bL[i]), 16, 0, 0);
        }
    };

    // ---- A geometry: thread owns 16 consecutive m at row t>>3, col0 (t&7)*16 ----
    const float* aSrc = adjB + (size_t)(t >> 3) * N_ + (t & 7) * 16;
    const unsigned aRow = (unsigned)(t >> 3);
    const unsigned aBase = aRow * 256u + (unsigned)((t & 7) * 32);
    const unsigned aSwz = (aRow & 7u) << 4;
    const int rsIdx0 = (t & 7) * 4;   // f32x4 index base within a 128-col slice

    f32x4 acc[2][2];
#pragma unroll
    for (int i = 0; i < 2; ++i)
#pragma unroll
        for (int jn = 0; jn < 2; ++jn) acc[i][jn] = (f32x4){0.f, 0.f, 0.f, 0.f};

    // ---- prologue: sRS DMA (1) + stage(0) issue (4 B-DMA + 4 A-reg loads) ----
    __builtin_amdgcn_global_load_lds(
        (const __attribute__((address_space(1))) void*)((const unsigned char*)rsB + t * 16),
        (__attribute__((address_space(3))) void*)((unsigned char*)sRS + t * 16), 16, 0, 0);
    issueB(0, 0);
    f32x4 aA[4];
#pragma unroll
    for (int j = 0; j < 4; ++j) aA[j] = *(const f32x4*)(aSrc + j * 4);
    asm volatile("s_waitcnt vmcnt(8)" ::: "memory");   // sRS landed
    __builtin_amdgcn_s_barrier();                      // sRS visible to all

    const int NITER = N_ / 128;  // 16
    for (int it = 0; it < NITER; ++it) {
        const int cur = it & 1;
        f32x4 nA[4];
#pragma unroll
        for (int j = 0; j < 4; ++j) nA[j] = aA[j];
        if (it + 1 < NITER) {
            issueB(cur ^ 1, (it + 1) * 128);
            const float* s = aSrc + (it + 1) * 128;
#pragma unroll
            for (int j = 0; j < 4; ++j) nA[j] = *(const f32x4*)(s + j * 4);
            asm volatile("s_waitcnt vmcnt(8)" ::: "memory");  // stage(it) landed; it+1 in flight
        } else {
            asm volatile("s_waitcnt vmcnt(0)" ::: "memory");
        }
        __builtin_amdgcn_sched_barrier(0);

        // write-late: scale A(it) by rs[m], cvt, store to sA[cur]
        {
            const f32x4* rsV = (const f32x4*)sRS + (it * 32 + rsIdx0);
            unsigned u[8];
#pragma unroll
            for (int j = 0; j < 4; ++j) {
                f32x4 xj = aA[j] * rsV[j];
                asm("v_cvt_pk_bf16_f32 %0, %1, %2" : "=v"(u[2 * j]) : "v"(xj[0]), "v"(xj[1]));
                asm("v_cvt_pk_bf16_f32 %0, %1, %2" : "=v"(u[2 * j + 1]) : "v"(xj[2]), "v"(xj[3]));
            }
            union { unsigned u[4]; bf16x8 v; } p0, p1;
            p0.u[0] = u[0]; p0.u[1] = u[1]; p0.u[2] = u[2]; p0.u[3] = u[3];
            p1.u[0] = u[4]; p1.u[1] = u[5]; p1.u[2] = u[6]; p1.u[3] = u[7];
            *(bf16x8*)(sA[cur] + (aBase ^ aSwz)) = p0.v;
            *(bf16x8*)(sA[cur] + ((aBase + 16) ^ aSwz)) = p1.v;
        }
        asm volatile("s_waitcnt lgkmcnt(0)" ::: "memory");
        __builtin_amdgcn_sched_barrier(0);
        __builtin_amdgcn_s_barrier();

        // compute(it): 16 MFMA/wave
        const unsigned char* pA = sA[cur];
        const unsigned char* pB = sB[cur];
#pragma unroll
        for (int kk = 0; kk < 4; ++kk) {
            bf16x8 a[2], bb[2];
#pragma unroll
            for (int i = 0; i < 2; ++i) {
                unsigned row = (unsigned)(wr * 32 + i * 16 + lr);
                unsigned byte = row * 256 + (unsigned)(kk * 64 + lh * 16);
                byte ^= (row & 7u) << 4;
                a[i] = *(const bf16x8*)(pA + byte);
            }
#pragma unroll
            for (int jn = 0; jn < 2; ++jn) {
                unsigned d = (unsigned)(wc * 32 + jn * 16 + lr);
                unsigned byte = d * 256 + (unsigned)(kk * 64 + lh * 16);
                byte ^= (d & 7u) << 4;
                bb[jn] = *(const bf16x8*)(pB + byte);
            }
#pragma unroll
            for (int i = 0; i < 2; ++i)
#pragma unroll
                for (int jn = 0; jn < 2; ++jn)
                    acc[i][jn] = __builtin_amdgcn_mfma_f32_16x16x32_bf16(a[i], bb[jn], acc[i][jn], 0, 0, 0);
        }
        __builtin_amdgcn_s_barrier();   // protect sA/sB[cur] before it+1 overwrites

#pragma unroll
        for (int j = 0; j < 4; ++j) aA[j] = nA[j];
    }

    // ---- epilogue: rs[n]*acc, relu, store ----
#pragma unroll
    for (int i = 0; i < 2; ++i) {
#pragma unroll
        for (int r = 0; r < 4; ++r) {
            int rowl = wr * 32 + i * 16 + lh * 4 + r;
            float rsn = sRS[R0 + rowl];
#pragma unroll
            for (int jn = 0; jn < 2; ++jn) {
                int d = wc * 32 + jn * 16 + lr;
                float v = acc[i][jn][r] * rsn;
                out[((size_t)(b * N_ + R0 + rowl)) * D_ + d] = fmaxf(v, 0.f);
            }
        }
    }
}

extern "C" void kernel_launch(void* const* d_in, const int* in_sizes, int n_in,
                              void* d_out, int out_size, void* d_ws, size_t ws_size,
                              hipStream_t stream) {
    const float* inputs = (const float*)d_in[0];   // [B,N,F]
    const float* adj    = (const float*)d_in[1];   // [B,N,N]
    const float* Wk     = (const float*)d_in[2];   // [F,D]
    const float* Wb     = (const float*)d_in[3];   // [D]
    float* out = (float*)d_out;

    float* rs = (float*)d_ws;                                    // 64 KB
    unsigned short* gt = (unsigned short*)((char*)d_ws + 65536); // 4 MB

    k_degfeat<<<256 + 4096, 256, 0, stream>>>(adj, inputs, Wk, Wb, rs, gt);
    k_gcn    <<<256, 512, 0, stream>>>(adj, gt, rs, out);
}